// Round 1
// baseline (583.385 us; speedup 1.0000x reference)
//
#include <hip/hip_runtime.h>
#include <math.h>

// Problem constants
constexpr int HD   = 512;    // hidden
constexpr int LL   = 1024;   // SES*SEQ
constexpr int MT   = 16384;  // B*L rows
constexpr int KNBR = 32;     // K neighbors

// ---------------- q = user_emb @ Wq^T + bq  (B x H) ----------------
__global__ __launch_bounds__(256) void gp_q(
    const float* __restrict__ u, const float* __restrict__ Wq,
    const float* __restrict__ bq, float* __restrict__ q)
{
    __shared__ float us[HD];
    const int b = blockIdx.x, tid = threadIdx.x;
    us[tid]       = u[b*HD + tid];
    us[tid + 256] = u[b*HD + tid + 256];
    __syncthreads();
    #pragma unroll
    for (int hb = 0; hb < 2; hb++) {
        const int h = tid + hb*256;
        const float* wr = &Wq[(size_t)h*HD];
        float acc = 0.f;
        for (int j = 0; j < HD; j += 4) {
            float4 w4 = *(const float4*)&wr[j];
            acc += us[j]*w4.x + us[j+1]*w4.y + us[j+2]*w4.z + us[j+3]*w4.w;
        }
        q[b*HD + h] = acc + bq[h];
    }
}

// ---------------- C = A @ W^T + bias (+ res), A:MTxHD, W:HDxHD ----------------
constexpr int BM = 64, BN = 64, BK = 32;

__global__ __launch_bounds__(256) void gp_gemm(
    const float* __restrict__ A, const float* __restrict__ W,
    const float* __restrict__ bias, const float* __restrict__ res,
    float* __restrict__ C)
{
    __shared__ float As[BK][BM + 4];
    __shared__ float Ws[BK][BN + 4];
    const int tid = threadIdx.x;
    const int tx = tid & 15, ty = tid >> 4;
    const int row0 = blockIdx.y * BM;
    const int col0 = blockIdx.x * BN;
    float acc[4][4] = {};

    for (int k0 = 0; k0 < HD; k0 += BK) {
        #pragma unroll
        for (int s = 0; s < 2; s++) {
            const int slot = tid + s*256;
            const int m  = slot >> 3;
            const int k4 = (slot & 7) << 2;
            float4 a = *(const float4*)&A[(size_t)(row0 + m)*HD + k0 + k4];
            As[k4+0][m] = a.x; As[k4+1][m] = a.y; As[k4+2][m] = a.z; As[k4+3][m] = a.w;
            float4 w = *(const float4*)&W[(size_t)(col0 + m)*HD + k0 + k4];
            Ws[k4+0][m] = w.x; Ws[k4+1][m] = w.y; Ws[k4+2][m] = w.z; Ws[k4+3][m] = w.w;
        }
        __syncthreads();
        #pragma unroll
        for (int kk = 0; kk < BK; kk++) {
            float4 ra4 = *(const float4*)&As[kk][ty << 2];
            float4 rw4 = *(const float4*)&Ws[kk][tx << 2];
            float ra[4] = {ra4.x, ra4.y, ra4.z, ra4.w};
            float rw[4] = {rw4.x, rw4.y, rw4.z, rw4.w};
            #pragma unroll
            for (int i = 0; i < 4; i++)
                #pragma unroll
                for (int j = 0; j < 4; j++)
                    acc[i][j] += ra[i] * rw[j];
        }
        __syncthreads();
    }

    const int n = col0 + (tx << 2);
    const float4 bb = *(const float4*)&bias[n];
    #pragma unroll
    for (int i = 0; i < 4; i++) {
        const int m = row0 + (ty << 2) + i;
        float4 o;
        o.x = acc[i][0] + bb.x; o.y = acc[i][1] + bb.y;
        o.z = acc[i][2] + bb.z; o.w = acc[i][3] + bb.w;
        if (res) {
            float4 r = *(const float4*)&res[(size_t)m*HD + n];
            o.x += r.x; o.y += r.y; o.z += r.z; o.w += r.w;
        }
        *(float4*)&C[(size_t)m*HD + n] = o;
    }
}

// ---------------- scores[m] = dot(q[b], k[m]) / sqrt(H) ----------------
__global__ __launch_bounds__(256) void gp_scores(
    const float* __restrict__ q, const float* __restrict__ k,
    float* __restrict__ scores)
{
    const int wave = threadIdx.x >> 6, lane = threadIdx.x & 63;
    const int m = blockIdx.x * 4 + wave;
    const int b = m >> 10;
    const float* kr = &k[(size_t)m * HD];
    const float* qr = &q[b * HD];
    float acc = 0.f;
    #pragma unroll
    for (int i = 0; i < 8; i++) {
        const int j = lane + i*64;
        acc += qr[j] * kr[j];
    }
    #pragma unroll
    for (int off = 32; off; off >>= 1) acc += __shfl_down(acc, off);
    if (lane == 0) scores[m] = acc * 0.04419417382415922f; // 1/sqrt(512)
}

// ---------------- gather + softmax + weighted sum of v ----------------
__global__ __launch_bounds__(256) void gp_attn(
    const float* __restrict__ scores, const int* __restrict__ index,
    const float* __restrict__ mask, const float* __restrict__ v,
    float* __restrict__ attn)
{
    __shared__ float s_s[KNBR];
    __shared__ float w_s[KNBR];
    __shared__ int   idx_s[KNBR];
    const int m = blockIdx.x;
    const int b = m >> 10, l = m & 1023;
    const int tid = threadIdx.x;

    if (tid < KNBR) {
        const int idx = index[l*KNBR + tid];
        idx_s[tid] = idx;
        s_s[tid] = scores[b*LL + idx] + mask[(size_t)m*KNBR + tid];
    }
    __syncthreads();
    if (tid < KNBR) {
        float mx = -1e30f;
        #pragma unroll
        for (int t = 0; t < KNBR; t++) mx = fmaxf(mx, s_s[t]);
        float sum = 0.f;
        #pragma unroll
        for (int t = 0; t < KNBR; t++) sum += __expf(s_s[t] - mx);
        w_s[tid] = __expf(s_s[tid] - mx) / sum;
    }
    __syncthreads();

    #pragma unroll
    for (int hb = 0; hb < 2; hb++) {
        const int h = tid + hb*256;
        float acc = 0.f;
        #pragma unroll 8
        for (int t = 0; t < KNBR; t++)
            acc += w_s[t] * v[((size_t)(b << 10) + idx_s[t])*HD + h];
        attn[(size_t)m*HD + h] = acc;
    }
}

// ---------------- LayerNorm (in place), one block per row ----------------
__global__ __launch_bounds__(256) void gp_ln(
    float* __restrict__ x, const float* __restrict__ g,
    const float* __restrict__ bt)
{
    const int m = blockIdx.x, tid = threadIdx.x;
    float* row = &x[(size_t)m*HD];
    const float v0 = row[tid];
    const float v1 = row[tid + 256];
    float sum = v0 + v1;
    float sq  = v0*v0 + v1*v1;
    #pragma unroll
    for (int off = 32; off; off >>= 1) {
        sum += __shfl_down(sum, off);
        sq  += __shfl_down(sq, off);
    }
    __shared__ float ssum[4], ssq[4];
    const int wave = tid >> 6;
    if ((tid & 63) == 0) { ssum[wave] = sum; ssq[wave] = sq; }
    __syncthreads();
    sum = ssum[0] + ssum[1] + ssum[2] + ssum[3];
    sq  = ssq[0]  + ssq[1]  + ssq[2]  + ssq[3];
    const float mu  = sum * (1.f/HD);
    const float var = sq * (1.f/HD) - mu*mu;
    const float inv = rsqrtf(var + 1e-12f);
    row[tid]       = (v0 - mu)*inv*g[tid]       + bt[tid];
    row[tid + 256] = (v1 - mu)*inv*g[tid + 256] + bt[tid + 256];
}

extern "C" void kernel_launch(void* const* d_in, const int* in_sizes, int n_in,
                              void* d_out, int out_size, void* d_ws, size_t ws_size,
                              hipStream_t stream) {
    const float* user_emb = (const float*)d_in[0];
    const float* item_emb = (const float*)d_in[1];   // (B, L, H) flat
    const float* mask     = (const float*)d_in[2];
    const int*   index    = (const int*)  d_in[3];
    const float* Wq = (const float*)d_in[4];  const float* bq = (const float*)d_in[5];
    const float* Wk = (const float*)d_in[6];  const float* bk = (const float*)d_in[7];
    const float* Wv = (const float*)d_in[8];  const float* bv = (const float*)d_in[9];
    const float* Wd = (const float*)d_in[10]; const float* bd = (const float*)d_in[11];
    const float* ln_g = (const float*)d_in[12];
    const float* ln_b = (const float*)d_in[13];

    float* out = (float*)d_out;
    float* ws  = (float*)d_ws;
    // workspace layout (floats)
    float* q      = ws;                        // 16*512          = 8192
    float* scores = ws + 8192;                 // 16384
    float* v      = ws + 24576;                // 16384*512       = 8388608
    float* attn   = v + (size_t)MT*HD;         // 8388608
    float* kbuf   = out;                       // k aliased into d_out (dead after scores)

    gp_q<<<16, 256, 0, stream>>>(user_emb, Wq, bq, q);

    dim3 gg(HD / BN, MT / BM);                 // (8, 256)
    gp_gemm<<<gg, 256, 0, stream>>>(item_emb, Wk, bk, nullptr, kbuf);
    gp_gemm<<<gg, 256, 0, stream>>>(item_emb, Wv, bv, nullptr, v);

    gp_scores<<<MT / 4, 256, 0, stream>>>(q, kbuf, scores);

    gp_attn<<<MT, 256, 0, stream>>>(scores, index, mask, v, attn);

    // x = attn @ Wd^T + bd + item_flat  -> d_out (k is dead now)
    gp_gemm<<<gg, 256, 0, stream>>>(attn, Wd, bd, item_emb, out);

    gp_ln<<<MT, 256, 0, stream>>>(out, ln_g, ln_b);
}

// Round 2
// 275.983 us; speedup vs baseline: 2.1138x; 2.1138x over previous
//
#include <hip/hip_runtime.h>
#include <math.h>

constexpr int HD   = 512;    // hidden
constexpr int LL   = 1024;   // SES*SEQ
constexpr int MT   = 16384;  // B*L rows
constexpr int KNBR = 32;     // K neighbors

typedef __attribute__((ext_vector_type(8))) short  bf16x8;  // 8 bf16 = 4 VGPRs
typedef __attribute__((ext_vector_type(4))) float  f32x4;
typedef __attribute__((ext_vector_type(8))) unsigned short us8;

__device__ inline float b2f(unsigned short u) {
    union { unsigned int i; float f; } v; v.i = (unsigned int)u << 16; return v.f;
}
__device__ inline unsigned short f2b(float x) {
    union { float f; unsigned int u; } v; v.f = x;
    unsigned int r = v.u + 0x7fff + ((v.u >> 16) & 1);
    return (unsigned short)(r >> 16);
}

// ---------------- fp32 -> bf16 conversion (grid covers n/4) ----------------
__global__ __launch_bounds__(256) void conv_bf(
    const float* __restrict__ s, unsigned short* __restrict__ d, int n)
{
    const int i = (blockIdx.x * 256 + threadIdx.x) * 4;
    if (i < n) {
        float4 v = *(const float4*)&s[i];
        ushort4 o;
        o.x = f2b(v.x); o.y = f2b(v.y); o.z = f2b(v.z); o.w = f2b(v.w);
        *(ushort4*)&d[i] = o;
    }
}

// ---------------- q = user_emb @ Wq^T + bq (B x H), fp32 ----------------
__global__ __launch_bounds__(256) void gp_q(
    const float* __restrict__ u, const float* __restrict__ Wq,
    const float* __restrict__ bq, float* __restrict__ q)
{
    __shared__ float us[HD];
    const int b = blockIdx.x, tid = threadIdx.x;
    us[tid]       = u[b*HD + tid];
    us[tid + 256] = u[b*HD + tid + 256];
    __syncthreads();
    #pragma unroll
    for (int hb = 0; hb < 2; hb++) {
        const int h = tid + hb*256;
        const float* wr = &Wq[(size_t)h*HD];
        float acc = 0.f;
        for (int j = 0; j < HD; j += 4) {
            float4 w4 = *(const float4*)&wr[j];
            acc += us[j]*w4.x + us[j+1]*w4.y + us[j+2]*w4.z + us[j+3]*w4.w;
        }
        q[b*HD + h] = acc + bq[h];
    }
}

// ------------- bf16 MFMA GEMM: C = A @ W^T + bias (+res) -------------
// A: MT x 512 bf16 (row-major, K-contig). W: 512 x 512 bf16 (N x K, K-contig).
// Output: fp32 (Cf) or bf16 (Cb). 128x128 tile, BK=32, 4 waves of 64x64.
__global__ __launch_bounds__(256) void gemm_bf(
    const unsigned short* __restrict__ A, const unsigned short* __restrict__ W,
    const float* __restrict__ bias, const float* __restrict__ res,
    float* __restrict__ Cf, unsigned short* __restrict__ Cb)
{
    __shared__ unsigned short As[128 * 32];   // 8 KB, chunk-swizzled
    __shared__ unsigned short Bs[128 * 32];   // 8 KB

    const int tid  = threadIdx.x;
    const int wave = tid >> 6, lane = tid & 63;
    const int wm = (wave >> 1) * 64;          // wave row offset in tile
    const int wn = (wave & 1)  * 64;          // wave col offset in tile
    const int row0 = blockIdx.x * 128;        // M
    const int col0 = blockIdx.y * 128;        // N

    // staging: each wave stages rows [wave*32, wave*32+32) of both A and B
    // tiles, two glds per operand (16 rows / 1 KB each).
    const int lrr = lane >> 2;                // 0..15 local row
    const int cc  = lane & 3;                 // stored chunk position
    int st_row[2], st_gchunk[2];
    #pragma unroll
    for (int t = 0; t < 2; t++) {
        const int m = wave*32 + t*16 + lrr;
        st_row[t]    = m;
        st_gchunk[t] = cc ^ ((m >> 1) & 3);   // which global 8-elem chunk
    }

    const int fr   = lane & 15;               // fragment row/col
    const int quad = lane >> 4;               // 0..3

    f32x4 acc[4][4];
    #pragma unroll
    for (int i = 0; i < 4; i++)
        #pragma unroll
        for (int j = 0; j < 4; j++)
            acc[i][j] = (f32x4){0.f, 0.f, 0.f, 0.f};

    // precompute fragment LDS offsets (ushort units)
    int a_off[4], b_off[4];
    #pragma unroll
    for (int i = 0; i < 4; i++) {
        const int m = wm + i*16 + fr;
        a_off[i] = m*32 + ((quad ^ ((m >> 1) & 3)) << 3);
        const int n = wn + i*16 + fr;
        b_off[i] = n*32 + ((quad ^ ((n >> 1) & 3)) << 3);
    }

    for (int k0 = 0; k0 < HD; k0 += 32) {
        #pragma unroll
        for (int t = 0; t < 2; t++) {
            const int m = st_row[t];
            const unsigned short* ga = &A[(size_t)(row0 + m)*HD + k0 + st_gchunk[t]*8];
            __builtin_amdgcn_global_load_lds(
                (const __attribute__((address_space(1))) void*)ga,
                (__attribute__((address_space(3))) void*)&As[(wave*32 + t*16)*32],
                16, 0, 0);
            const unsigned short* gw = &W[(size_t)(col0 + m)*HD + k0 + st_gchunk[t]*8];
            __builtin_amdgcn_global_load_lds(
                (const __attribute__((address_space(1))) void*)gw,
                (__attribute__((address_space(3))) void*)&Bs[(wave*32 + t*16)*32],
                16, 0, 0);
        }
        __syncthreads();   // drains vmcnt (glds) before LDS reads

        bf16x8 af[4], bfr[4];
        #pragma unroll
        for (int i = 0; i < 4; i++) {
            af[i]  = *(const bf16x8*)&As[a_off[i]];
            bfr[i] = *(const bf16x8*)&Bs[b_off[i]];
        }
        #pragma unroll
        for (int i = 0; i < 4; i++)
            #pragma unroll
            for (int j = 0; j < 4; j++)
                acc[i][j] = __builtin_amdgcn_mfma_f32_16x16x32_bf16(
                    af[i], bfr[j], acc[i][j], 0, 0, 0);
        __syncthreads();   // protect LDS reuse next iteration
    }

    // epilogue: D row = quad*4+r (M), col = fr (N) within each 16x16 tile
    #pragma unroll
    for (int j = 0; j < 4; j++) {
        const int col = col0 + wn + j*16 + fr;
        const float bb = bias[col];
        #pragma unroll
        for (int i = 0; i < 4; i++) {
            #pragma unroll
            for (int r = 0; r < 4; r++) {
                const int row = row0 + wm + i*16 + quad*4 + r;
                const size_t o = (size_t)row*HD + col;
                float val = acc[i][j][r] + bb;
                if (res) val += res[o];
                if (Cf) Cf[o] = val;
                else    Cb[o] = f2b(val);
            }
        }
    }
}

// ---------------- scores[m] = dot(q[b], k[m]) / sqrt(H) ----------------
__global__ __launch_bounds__(256) void gp_scores(
    const float* __restrict__ q, const unsigned short* __restrict__ k,
    float* __restrict__ scores)
{
    const int wave = threadIdx.x >> 6, lane = threadIdx.x & 63;
    const int m = blockIdx.x * 4 + wave;
    const int b = m >> 10;
    const us8 kv = *(const us8*)&k[(size_t)m * HD + lane*8];
    const float* qr = &q[b*HD + lane*8];
    const float4 q0 = *(const float4*)qr;
    const float4 q1 = *(const float4*)(qr + 4);
    float acc = q0.x*b2f(kv[0]) + q0.y*b2f(kv[1]) + q0.z*b2f(kv[2]) + q0.w*b2f(kv[3])
              + q1.x*b2f(kv[4]) + q1.y*b2f(kv[5]) + q1.z*b2f(kv[6]) + q1.w*b2f(kv[7]);
    #pragma unroll
    for (int off = 32; off; off >>= 1) acc += __shfl_down(acc, off);
    if (lane == 0) scores[m] = acc * 0.04419417382415922f; // 1/sqrt(512)
}

// ------------- gather + softmax + weighted sum of v (bf16) -------------
__global__ __launch_bounds__(256) void gp_attn(
    const float* __restrict__ scores, const int* __restrict__ index,
    const float* __restrict__ mask, const unsigned short* __restrict__ v,
    unsigned short* __restrict__ attn)
{
    __shared__ float s_s[KNBR];
    __shared__ float w_s[KNBR];
    __shared__ int   idx_s[KNBR];
    const int m = blockIdx.x;
    const int b = m >> 10, l = m & 1023;
    const int tid = threadIdx.x;

    if (tid < KNBR) {
        const int idx = index[l*KNBR + tid];
        idx_s[tid] = idx;
        s_s[tid] = scores[b*LL + idx] + mask[(size_t)m*KNBR + tid];
    }
    __syncthreads();
    if (tid < KNBR) {
        float mx = -1e30f;
        #pragma unroll
        for (int t = 0; t < KNBR; t++) mx = fmaxf(mx, s_s[t]);
        float sum = 0.f;
        #pragma unroll
        for (int t = 0; t < KNBR; t++) sum += __expf(s_s[t] - mx);
        w_s[tid] = __expf(s_s[tid] - mx) / sum;
    }
    __syncthreads();

    const int h = tid * 2;
    const unsigned short* vb = &v[((size_t)(b << 10))*HD + h];
    float a0 = 0.f, a1 = 0.f;
    #pragma unroll 8
    for (int t = 0; t < KNBR; t++) {
        const unsigned int pv = *(const unsigned int*)&vb[(size_t)idx_s[t]*HD];
        const float w = w_s[t];
        a0 += w * b2f((unsigned short)(pv & 0xffff));
        a1 += w * b2f((unsigned short)(pv >> 16));
    }
    const unsigned int o = (unsigned int)f2b(a0) | ((unsigned int)f2b(a1) << 16);
    *(unsigned int*)&attn[(size_t)m*HD + h] = o;
}

// ---------------- LayerNorm (in place), one block per row ----------------
__global__ __launch_bounds__(256) void gp_ln(
    float* __restrict__ x, const float* __restrict__ g,
    const float* __restrict__ bt)
{
    const int m = blockIdx.x, tid = threadIdx.x;
    float* row = &x[(size_t)m*HD];
    const float v0 = row[tid];
    const float v1 = row[tid + 256];
    float sum = v0 + v1;
    float sq  = v0*v0 + v1*v1;
    #pragma unroll
    for (int off = 32; off; off >>= 1) {
        sum += __shfl_down(sum, off);
        sq  += __shfl_down(sq, off);
    }
    __shared__ float ssum[4], ssq[4];
    const int wave = tid >> 6;
    if ((tid & 63) == 0) { ssum[wave] = sum; ssq[wave] = sq; }
    __syncthreads();
    sum = ssum[0] + ssum[1] + ssum[2] + ssum[3];
    sq  = ssq[0]  + ssq[1]  + ssq[2]  + ssq[3];
    const float mu  = sum * (1.f/HD);
    const float var = sq * (1.f/HD) - mu*mu;
    const float inv = rsqrtf(var + 1e-12f);
    row[tid]       = (v0 - mu)*inv*g[tid]       + bt[tid];
    row[tid + 256] = (v1 - mu)*inv*g[tid + 256] + bt[tid + 256];
}

extern "C" void kernel_launch(void* const* d_in, const int* in_sizes, int n_in,
                              void* d_out, int out_size, void* d_ws, size_t ws_size,
                              hipStream_t stream) {
    const float* user_emb = (const float*)d_in[0];
    const float* item_emb = (const float*)d_in[1];   // (B, L, H) flat fp32
    const float* mask     = (const float*)d_in[2];
    const int*   index    = (const int*)  d_in[3];
    const float* Wq = (const float*)d_in[4];  const float* bq = (const float*)d_in[5];
    const float* Wk = (const float*)d_in[6];  const float* bk = (const float*)d_in[7];
    const float* Wv = (const float*)d_in[8];  const float* bv = (const float*)d_in[9];
    const float* Wd = (const float*)d_in[10]; const float* bd = (const float*)d_in[11];
    const float* ln_g = (const float*)d_in[12];
    const float* ln_b = (const float*)d_in[13];

    float* out = (float*)d_out;

    // workspace layout (bytes, all 16B-aligned)
    char* p = (char*)d_ws;
    unsigned short* item_bf = (unsigned short*)p; p += (size_t)MT*HD*2;   // 16.78 MB
    unsigned short* v_bf    = (unsigned short*)p; p += (size_t)MT*HD*2;
    unsigned short* attn_bf = (unsigned short*)p; p += (size_t)MT*HD*2;
    unsigned short* Wk_bf   = (unsigned short*)p; p += (size_t)HD*HD*2;
    unsigned short* Wv_bf   = (unsigned short*)p; p += (size_t)HD*HD*2;
    unsigned short* Wd_bf   = (unsigned short*)p; p += (size_t)HD*HD*2;
    float* q      = (float*)p; p += 16*HD*4;
    float* scores = (float*)p; p += MT*4;
    unsigned short* k_bf = (unsigned short*)d_out;  // dead before dense GEMM writes

    // bf16 conversions
    conv_bf<<<(MT*HD/4 + 255)/256, 256, 0, stream>>>(item_emb, item_bf, MT*HD);
    conv_bf<<<(HD*HD/4 + 255)/256, 256, 0, stream>>>(Wk, Wk_bf, HD*HD);
    conv_bf<<<(HD*HD/4 + 255)/256, 256, 0, stream>>>(Wv, Wv_bf, HD*HD);
    conv_bf<<<(HD*HD/4 + 255)/256, 256, 0, stream>>>(Wd, Wd_bf, HD*HD);

    gp_q<<<16, 256, 0, stream>>>(user_emb, Wq, bq, q);

    dim3 gg(MT/128, HD/128);   // (128, 4)
    gemm_bf<<<gg, 256, 0, stream>>>(item_bf, Wk_bf, bk, nullptr, nullptr, k_bf);
    gemm_bf<<<gg, 256, 0, stream>>>(item_bf, Wv_bf, bv, nullptr, nullptr, v_bf);

    gp_scores<<<MT/4, 256, 0, stream>>>(q, k_bf, scores);
    gp_attn<<<MT, 256, 0, stream>>>(scores, index, mask, v_bf, attn_bf);

    // x = attn @ Wd^T + bd + item_flat -> d_out (fp32)
    gemm_bf<<<gg, 256, 0, stream>>>(attn_bf, Wd_bf, bd, item_emb, out, nullptr);

    gp_ln<<<MT, 256, 0, stream>>>(out, ln_g, ln_b);
}

// Round 3
// 236.181 us; speedup vs baseline: 2.4701x; 1.1685x over previous
//
#include <hip/hip_runtime.h>
#include <math.h>

constexpr int HD   = 512;    // hidden
constexpr int LL   = 1024;   // SES*SEQ
constexpr int MT   = 16384;  // B*L rows
constexpr int KNBR = 32;     // K neighbors
constexpr int KVS  = 1024;   // kv row stride (k cols 0-511, v cols 512-1023)

typedef __attribute__((ext_vector_type(8))) short  bf16x8;  // 8 bf16 = 4 VGPRs
typedef __attribute__((ext_vector_type(4))) float  f32x4;
typedef __attribute__((ext_vector_type(8))) unsigned short us8;

__device__ inline float b2f(unsigned short u) {
    union { unsigned int i; float f; } v; v.i = (unsigned int)u << 16; return v.f;
}
__device__ inline float b2f_lo(unsigned int u) {
    union { unsigned int i; float f; } v; v.i = u << 16; return v.f;
}
__device__ inline float b2f_hi(unsigned int u) {
    union { unsigned int i; float f; } v; v.i = u & 0xffff0000u; return v.f;
}
__device__ inline unsigned short f2b(float x) {
    union { float f; unsigned int u; } v; v.f = x;
    unsigned int r = v.u + 0x7fff + ((v.u >> 16) & 1);
    return (unsigned short)(r >> 16);
}

// ---------------- fp32 -> bf16 conversion (grid covers n/4) ----------------
__global__ __launch_bounds__(256) void conv_bf(
    const float* __restrict__ s, unsigned short* __restrict__ d, int n)
{
    const int i = (blockIdx.x * 256 + threadIdx.x) * 4;
    if (i < n) {
        float4 v = *(const float4*)&s[i];
        ushort4 o;
        o.x = f2b(v.x); o.y = f2b(v.y); o.z = f2b(v.z); o.w = f2b(v.w);
        *(ushort4*)&d[i] = o;
    }
}

// -------- q = user_emb @ Wq^T + bq (B x H), one wave per (b,h) --------
__global__ __launch_bounds__(256) void gp_q(
    const float* __restrict__ u, const float* __restrict__ Wq,
    const float* __restrict__ bq, float* __restrict__ q)
{
    const int wid  = blockIdx.x * 4 + (threadIdx.x >> 6);   // 0..8191
    const int lane = threadIdx.x & 63;
    const int b = wid >> 9, h = wid & 511;
    const float* ur = &u[b*HD + lane*8];
    const float* wr = &Wq[(size_t)h*HD + lane*8];
    const float4 u0 = *(const float4*)ur,     u1 = *(const float4*)(ur+4);
    const float4 w0 = *(const float4*)wr,     w1 = *(const float4*)(wr+4);
    float acc = u0.x*w0.x + u0.y*w0.y + u0.z*w0.z + u0.w*w0.w
              + u1.x*w1.x + u1.y*w1.y + u1.z*w1.z + u1.w*w1.w;
    #pragma unroll
    for (int off = 32; off; off >>= 1) acc += __shfl_down(acc, off);
    if (lane == 0) q[b*HD + h] = acc + bq[h];
}

// ------------- bf16 MFMA GEMM: C = A @ W^T + bias (+res) -------------
// A: MT x 512 bf16 (row-major, K-contig). W: NS x 512 bf16 (N x K, K-contig).
// C row stride NS. Output fp32 (Cf) or bf16 (Cb). 128x128 tile, BK=32.
__global__ __launch_bounds__(256) void gemm_bf(
    const unsigned short* __restrict__ A, const unsigned short* __restrict__ W,
    const float* __restrict__ bias0, const float* __restrict__ bias1,
    const float* __restrict__ res,
    float* __restrict__ Cf, unsigned short* __restrict__ Cb, int NS)
{
    __shared__ unsigned short As[128 * 32];   // 8 KB, chunk-swizzled
    __shared__ unsigned short Bs[128 * 32];   // 8 KB

    const int tid  = threadIdx.x;
    const int wave = tid >> 6, lane = tid & 63;
    const int wm = (wave >> 1) * 64;          // wave row offset in tile
    const int wn = (wave & 1)  * 64;          // wave col offset in tile
    const int row0 = blockIdx.x * 128;        // M
    const int col0 = blockIdx.y * 128;        // N

    const int lrr = lane >> 2;                // 0..15 local row
    const int cc  = lane & 3;                 // stored chunk position
    int st_row[2], st_gchunk[2];
    #pragma unroll
    for (int t = 0; t < 2; t++) {
        const int m = wave*32 + t*16 + lrr;
        st_row[t]    = m;
        st_gchunk[t] = cc ^ ((m >> 1) & 3);   // which global 8-elem chunk
    }

    const int fr   = lane & 15;               // fragment row/col
    const int quad = lane >> 4;               // 0..3

    f32x4 acc[4][4];
    #pragma unroll
    for (int i = 0; i < 4; i++)
        #pragma unroll
        for (int j = 0; j < 4; j++)
            acc[i][j] = (f32x4){0.f, 0.f, 0.f, 0.f};

    int a_off[4], b_off[4];
    #pragma unroll
    for (int i = 0; i < 4; i++) {
        const int m = wm + i*16 + fr;
        a_off[i] = m*32 + ((quad ^ ((m >> 1) & 3)) << 3);
        const int n = wn + i*16 + fr;
        b_off[i] = n*32 + ((quad ^ ((n >> 1) & 3)) << 3);
    }

    for (int k0 = 0; k0 < HD; k0 += 32) {
        #pragma unroll
        for (int t = 0; t < 2; t++) {
            const int m = st_row[t];
            const unsigned short* ga = &A[(size_t)(row0 + m)*HD + k0 + st_gchunk[t]*8];
            __builtin_amdgcn_global_load_lds(
                (const __attribute__((address_space(1))) void*)ga,
                (__attribute__((address_space(3))) void*)&As[(wave*32 + t*16)*32],
                16, 0, 0);
            const unsigned short* gw = &W[(size_t)(col0 + m)*HD + k0 + st_gchunk[t]*8];
            __builtin_amdgcn_global_load_lds(
                (const __attribute__((address_space(1))) void*)gw,
                (__attribute__((address_space(3))) void*)&Bs[(wave*32 + t*16)*32],
                16, 0, 0);
        }
        __syncthreads();

        bf16x8 af[4], bfr[4];
        #pragma unroll
        for (int i = 0; i < 4; i++) {
            af[i]  = *(const bf16x8*)&As[a_off[i]];
            bfr[i] = *(const bf16x8*)&Bs[b_off[i]];
        }
        #pragma unroll
        for (int i = 0; i < 4; i++)
            #pragma unroll
            for (int j = 0; j < 4; j++)
                acc[i][j] = __builtin_amdgcn_mfma_f32_16x16x32_bf16(
                    af[i], bfr[j], acc[i][j], 0, 0, 0);
        __syncthreads();
    }

    // epilogue: D row = quad*4+r (M), col = fr (N) within each 16x16 tile
    #pragma unroll
    for (int j = 0; j < 4; j++) {
        const int col = col0 + wn + j*16 + fr;
        const float bb = (col < HD) ? bias0[col] : bias1[col - HD];
        #pragma unroll
        for (int i = 0; i < 4; i++) {
            #pragma unroll
            for (int r = 0; r < 4; r++) {
                const int row = row0 + wm + i*16 + quad*4 + r;
                const size_t o = (size_t)row*NS + col;
                float val = acc[i][j][r] + bb;
                if (res) val += res[(size_t)row*HD + col];
                if (Cf) Cf[o] = val;
                else    Cb[o] = f2b(val);
            }
        }
    }
}

// ---------- scores[m] = dot(q[b], kv[m][0:512]) / sqrt(H) ----------
__global__ __launch_bounds__(256) void gp_scores(
    const float* __restrict__ q, const unsigned short* __restrict__ kv,
    float* __restrict__ scores)
{
    const int wave = threadIdx.x >> 6, lane = threadIdx.x & 63;
    const int m = blockIdx.x * 4 + wave;
    const int b = m >> 10;
    const us8 kvv = *(const us8*)&kv[(size_t)m * KVS + lane*8];
    const float* qr = &q[b*HD + lane*8];
    const float4 q0 = *(const float4*)qr;
    const float4 q1 = *(const float4*)(qr + 4);
    float acc = q0.x*b2f(kvv[0]) + q0.y*b2f(kvv[1]) + q0.z*b2f(kvv[2]) + q0.w*b2f(kvv[3])
              + q1.x*b2f(kvv[4]) + q1.y*b2f(kvv[5]) + q1.z*b2f(kvv[6]) + q1.w*b2f(kvv[7]);
    #pragma unroll
    for (int off = 32; off; off >>= 1) acc += __shfl_down(acc, off);
    if (lane == 0) scores[m] = acc * 0.04419417382415922f; // 1/sqrt(512)
}

// ----- gather + softmax + weighted sum of v: one wave per row -----
__global__ __launch_bounds__(256) void gp_attn(
    const float* __restrict__ scores, const int* __restrict__ index,
    const float* __restrict__ mask, const unsigned short* __restrict__ kv,
    unsigned short* __restrict__ attn)
{
    const int m = blockIdx.x * 4 + (threadIdx.x >> 6);
    const int lane = threadIdx.x & 63;
    const int b = m >> 10, l = m & 1023;

    // lanes 0-31 and 32-63 hold duplicate copies of the 32 (idx, score) pairs
    const int t = lane & 31;
    const int idx = index[l*KNBR + t];
    const float s = scores[b*LL + idx] + mask[(size_t)m*KNBR + t];

    // softmax across the 32-group, in-register butterflies
    float mx = s;
    #pragma unroll
    for (int off = 16; off; off >>= 1) mx = fmaxf(mx, __shfl_xor(mx, off));
    const float e = __expf(s - mx);
    float sum = e;
    #pragma unroll
    for (int off = 16; off; off >>= 1) sum += __shfl_xor(sum, off);
    const float w = e / sum;

    // lane covers h = lane*8 .. lane*8+7 (v = kv cols 512..1023)
    const unsigned short* vbase = kv + (size_t)(b << 10) * KVS + HD + lane*8;
    float a[8] = {};
    #pragma unroll 8
    for (int t2 = 0; t2 < KNBR; t2++) {
        const int   it = __shfl(idx, t2);
        const float wt = __shfl(w,   t2);
        const uint4 pv = *(const uint4*)(vbase + (size_t)it*KVS);
        a[0] += wt * b2f_lo(pv.x); a[1] += wt * b2f_hi(pv.x);
        a[2] += wt * b2f_lo(pv.y); a[3] += wt * b2f_hi(pv.y);
        a[4] += wt * b2f_lo(pv.z); a[5] += wt * b2f_hi(pv.z);
        a[6] += wt * b2f_lo(pv.w); a[7] += wt * b2f_hi(pv.w);
    }
    uint4 o;
    o.x = (unsigned int)f2b(a[0]) | ((unsigned int)f2b(a[1]) << 16);
    o.y = (unsigned int)f2b(a[2]) | ((unsigned int)f2b(a[3]) << 16);
    o.z = (unsigned int)f2b(a[4]) | ((unsigned int)f2b(a[5]) << 16);
    o.w = (unsigned int)f2b(a[6]) | ((unsigned int)f2b(a[7]) << 16);
    *(uint4*)&attn[(size_t)m*HD + lane*8] = o;
}

// ---------------- LayerNorm (in place), one block per row ----------------
__global__ __launch_bounds__(256) void gp_ln(
    float* __restrict__ x, const float* __restrict__ g,
    const float* __restrict__ bt)
{
    const int m = blockIdx.x, tid = threadIdx.x;
    float* row = &x[(size_t)m*HD];
    const float v0 = row[tid];
    const float v1 = row[tid + 256];
    float sum = v0 + v1;
    float sq  = v0*v0 + v1*v1;
    #pragma unroll
    for (int off = 32; off; off >>= 1) {
        sum += __shfl_down(sum, off);
        sq  += __shfl_down(sq, off);
    }
    __shared__ float ssum[4], ssq[4];
    const int wave = tid >> 6;
    if ((tid & 63) == 0) { ssum[wave] = sum; ssq[wave] = sq; }
    __syncthreads();
    sum = ssum[0] + ssum[1] + ssum[2] + ssum[3];
    sq  = ssq[0]  + ssq[1]  + ssq[2]  + ssq[3];
    const float mu  = sum * (1.f/HD);
    const float var = sq * (1.f/HD) - mu*mu;
    const float inv = rsqrtf(var + 1e-12f);
    row[tid]       = (v0 - mu)*inv*g[tid]       + bt[tid];
    row[tid + 256] = (v1 - mu)*inv*g[tid + 256] + bt[tid + 256];
}

extern "C" void kernel_launch(void* const* d_in, const int* in_sizes, int n_in,
                              void* d_out, int out_size, void* d_ws, size_t ws_size,
                              hipStream_t stream) {
    const float* user_emb = (const float*)d_in[0];
    const float* item_emb = (const float*)d_in[1];
    const float* mask     = (const float*)d_in[2];
    const int*   index    = (const int*)  d_in[3];
    const float* Wq = (const float*)d_in[4];  const float* bq = (const float*)d_in[5];
    const float* Wk = (const float*)d_in[6];  const float* bk = (const float*)d_in[7];
    const float* Wv = (const float*)d_in[8];  const float* bv = (const float*)d_in[9];
    const float* Wd = (const float*)d_in[10]; const float* bd = (const float*)d_in[11];
    const float* ln_g = (const float*)d_in[12];
    const float* ln_b = (const float*)d_in[13];

    float* out = (float*)d_out;

    // workspace layout (bytes, all 16B-aligned)
    char* p = (char*)d_ws;
    unsigned short* item_bf = (unsigned short*)p; p += (size_t)MT*HD*2;     // 16.8 MB
    unsigned short* kv_bf   = (unsigned short*)p; p += (size_t)MT*KVS*2;    // 33.5 MB
    unsigned short* attn_bf = (unsigned short*)p; p += (size_t)MT*HD*2;     // 16.8 MB
    unsigned short* Wkv_bf  = (unsigned short*)p; p += (size_t)2*HD*HD*2;   // 1 MB
    unsigned short* Wd_bf   = (unsigned short*)p; p += (size_t)HD*HD*2;     // 0.5 MB
    float* q      = (float*)p; p += 16*HD*4;
    float* scores = (float*)p; p += MT*4;

    // bf16 conversions (Wk -> Wkv rows 0-511, Wv -> rows 512-1023)
    conv_bf<<<(MT*HD/4 + 255)/256, 256, 0, stream>>>(item_emb, item_bf, MT*HD);
    conv_bf<<<(HD*HD/4 + 255)/256, 256, 0, stream>>>(Wk, Wkv_bf, HD*HD);
    conv_bf<<<(HD*HD/4 + 255)/256, 256, 0, stream>>>(Wv, Wkv_bf + (size_t)HD*HD, HD*HD);
    conv_bf<<<(HD*HD/4 + 255)/256, 256, 0, stream>>>(Wd, Wd_bf, HD*HD);

    gp_q<<<2048, 256, 0, stream>>>(user_emb, Wq, bq, q);

    // fused K+V GEMM: C = item @ [Wk;Wv]^T, N=1024
    dim3 gkv(MT/128, KVS/128);   // (128, 8)
    gemm_bf<<<gkv, 256, 0, stream>>>(item_bf, Wkv_bf, bk, bv, nullptr,
                                     nullptr, kv_bf, KVS);

    gp_scores<<<MT/4, 256, 0, stream>>>(q, kv_bf, scores);
    gp_attn<<<MT/4, 256, 0, stream>>>(scores, index, mask, kv_bf, attn_bf);

    // x = attn @ Wd^T + bd + item_flat -> d_out (fp32)
    dim3 gd(MT/128, HD/128);     // (128, 4)
    gemm_bf<<<gd, 256, 0, stream>>>(attn_bf, Wd_bf, bd, bd, item_emb,
                                    out, nullptr, HD);

    gp_ln<<<MT, 256, 0, stream>>>(out, ln_g, ln_b);
}

// Round 4
// 202.909 us; speedup vs baseline: 2.8751x; 1.1640x over previous
//
#include <hip/hip_runtime.h>
#include <math.h>

constexpr int HD   = 512;    // hidden
constexpr int LL   = 1024;   // SES*SEQ
constexpr int MT   = 16384;  // B*L rows
constexpr int KNBR = 32;     // K neighbors
constexpr float SCL = 0.04419417382415922f;  // 1/sqrt(512)

typedef __attribute__((ext_vector_type(8))) short  bf16x8;  // 8 bf16 = 4 VGPRs
typedef __attribute__((ext_vector_type(4))) float  f32x4;
typedef __attribute__((ext_vector_type(8))) unsigned short us8;

__device__ inline float b2f(unsigned short u) {
    union { unsigned int i; float f; } v; v.i = (unsigned int)u << 16; return v.f;
}
__device__ inline float b2f_lo(unsigned int u) {
    union { unsigned int i; float f; } v; v.i = u << 16; return v.f;
}
__device__ inline float b2f_hi(unsigned int u) {
    union { unsigned int i; float f; } v; v.i = u & 0xffff0000u; return v.f;
}
__device__ inline unsigned short f2b(float x) {
    union { float f; unsigned int u; } v; v.f = x;
    unsigned int r = v.u + 0x7fff + ((v.u >> 16) & 1);
    return (unsigned short)(r >> 16);
}

// ---------------- fp32 -> bf16 conversion ----------------
__global__ __launch_bounds__(256) void conv_bf(
    const float* __restrict__ s, unsigned short* __restrict__ d, int n)
{
    const int i = (blockIdx.x * 256 + threadIdx.x) * 4;
    if (i < n) {
        float4 v = *(const float4*)&s[i];
        ushort4 o;
        o.x = f2b(v.x); o.y = f2b(v.y); o.z = f2b(v.z); o.w = f2b(v.w);
        *(ushort4*)&d[i] = o;
    }
}

// ------- all three weight matrices in one launch: Wk,Wv -> Wkv; Wd -> Wdb -------
__global__ __launch_bounds__(256) void conv_w3(
    const float* __restrict__ Wk, const float* __restrict__ Wv,
    const float* __restrict__ Wd, unsigned short* __restrict__ Wkv,
    unsigned short* __restrict__ Wdb)
{
    const int n = HD*HD;
    const int i = (blockIdx.x * 256 + threadIdx.x) * 4;
    const float* s; unsigned short* d; int off;
    if (i < n)            { s = Wk; d = Wkv;     off = i; }
    else if (i < 2*n)     { s = Wv; d = Wkv + n; off = i - n; }
    else                  { s = Wd; d = Wdb;     off = i - 2*n; }
    float4 v = *(const float4*)&s[off];
    ushort4 o;
    o.x = f2b(v.x); o.y = f2b(v.y); o.z = f2b(v.z); o.w = f2b(v.w);
    *(ushort4*)&d[off] = o;
}

// -------- q = user_emb @ Wq^T + bq (B x H), one wave per (b,h) --------
__global__ __launch_bounds__(256) void gp_q(
    const float* __restrict__ u, const float* __restrict__ Wq,
    const float* __restrict__ bq, float* __restrict__ q)
{
    const int wid  = blockIdx.x * 4 + (threadIdx.x >> 6);   // 0..8191
    const int lane = threadIdx.x & 63;
    const int b = wid >> 9, h = wid & 511;
    const float* ur = &u[b*HD + lane*8];
    const float* wr = &Wq[(size_t)h*HD + lane*8];
    const float4 u0 = *(const float4*)ur,     u1 = *(const float4*)(ur+4);
    const float4 w0 = *(const float4*)wr,     w1 = *(const float4*)(wr+4);
    float acc = u0.x*w0.x + u0.y*w0.y + u0.z*w0.z + u0.w*w0.w
              + u1.x*w1.x + u1.y*w1.y + u1.z*w1.z + u1.w*w1.w;
    #pragma unroll
    for (int off = 32; off; off >>= 1) acc += __shfl_down(acc, off);
    if (lane == 0) q[b*HD + h] = acc + bq[h];
}

// ------- scores[b*LL + l] = dot(q[b], bk) * SCL  (init for atomics) -------
__global__ __launch_bounds__(256) void scores_init(
    const float* __restrict__ q, const float* __restrict__ bk,
    float* __restrict__ scores)
{
    const int b = blockIdx.x, tid = threadIdx.x;
    float p = q[b*HD + tid]*bk[tid] + q[b*HD + tid + 256]*bk[tid + 256];
    #pragma unroll
    for (int off = 32; off; off >>= 1) p += __shfl_down(p, off);
    __shared__ float sp[4];
    if ((tid & 63) == 0) sp[tid >> 6] = p;
    __syncthreads();
    const float s = (sp[0] + sp[1] + sp[2] + sp[3]) * SCL;
    float4 o = {s, s, s, s};
    *(float4*)&scores[b*LL + tid*4] = o;
}

// ------- fused KV GEMM: k-half -> score partials (atomic), v-half -> v_bf -------
// A: MT x 512 bf16. Wkv: 1024 x 512 bf16 (k rows 0-511, v rows 512-1023).
__global__ __launch_bounds__(256) void gemm_kv(
    const unsigned short* __restrict__ A, const unsigned short* __restrict__ W,
    const float* __restrict__ q, const float* __restrict__ bv,
    float* __restrict__ scores, unsigned short* __restrict__ v_bf)
{
    __shared__ unsigned short As[128 * 32];   // 8 KB, chunk-swizzled
    __shared__ unsigned short Bs[128 * 32];   // 8 KB

    const int tid  = threadIdx.x;
    const int wave = tid >> 6, lane = tid & 63;
    const int wm = (wave >> 1) * 64;
    const int wn = (wave & 1)  * 64;
    const int row0 = blockIdx.x * 128;
    const int col0 = blockIdx.y * 128;        // 0..895; <512 = k half

    const int lrr = lane >> 2;
    const int cc  = lane & 3;
    int st_row[2], st_gchunk[2];
    #pragma unroll
    for (int t = 0; t < 2; t++) {
        const int m = wave*32 + t*16 + lrr;
        st_row[t]    = m;
        st_gchunk[t] = cc ^ ((m >> 1) & 3);
    }

    const int fr   = lane & 15;
    const int quad = lane >> 4;

    f32x4 acc[4][4];
    #pragma unroll
    for (int i = 0; i < 4; i++)
        #pragma unroll
        for (int j = 0; j < 4; j++)
            acc[i][j] = (f32x4){0.f, 0.f, 0.f, 0.f};

    int a_off[4], b_off[4];
    #pragma unroll
    for (int i = 0; i < 4; i++) {
        const int m = wm + i*16 + fr;
        a_off[i] = m*32 + ((quad ^ ((m >> 1) & 3)) << 3);
        const int n = wn + i*16 + fr;
        b_off[i] = n*32 + ((quad ^ ((n >> 1) & 3)) << 3);
    }

    for (int k0 = 0; k0 < HD; k0 += 32) {
        #pragma unroll
        for (int t = 0; t < 2; t++) {
            const int m = st_row[t];
            const unsigned short* ga = &A[(size_t)(row0 + m)*HD + k0 + st_gchunk[t]*8];
            __builtin_amdgcn_global_load_lds(
                (const __attribute__((address_space(1))) void*)ga,
                (__attribute__((address_space(3))) void*)&As[(wave*32 + t*16)*32],
                16, 0, 0);
            const unsigned short* gw = &W[(size_t)(col0 + m)*HD + k0 + st_gchunk[t]*8];
            __builtin_amdgcn_global_load_lds(
                (const __attribute__((address_space(1))) void*)gw,
                (__attribute__((address_space(3))) void*)&Bs[(wave*32 + t*16)*32],
                16, 0, 0);
        }
        __syncthreads();

        bf16x8 af[4], bfr[4];
        #pragma unroll
        for (int i = 0; i < 4; i++) {
            af[i]  = *(const bf16x8*)&As[a_off[i]];
            bfr[i] = *(const bf16x8*)&Bs[b_off[i]];
        }
        #pragma unroll
        for (int i = 0; i < 4; i++)
            #pragma unroll
            for (int j = 0; j < 4; j++)
                acc[i][j] = __builtin_amdgcn_mfma_f32_16x16x32_bf16(
                    af[i], bfr[j], acc[i][j], 0, 0, 0);
        __syncthreads();
    }

    if (col0 < HD) {
        // k half: fold into score partials. score[m] += SCL * dot(q[b], k[m,:])
        const int b = row0 >> 10;
        float qv[4];
        #pragma unroll
        for (int j = 0; j < 4; j++)
            qv[j] = q[b*HD + col0 + wn + j*16 + fr];
        #pragma unroll
        for (int i = 0; i < 4; i++) {
            #pragma unroll
            for (int r = 0; r < 4; r++) {
                float p = acc[i][0][r]*qv[0] + acc[i][1][r]*qv[1]
                        + acc[i][2][r]*qv[2] + acc[i][3][r]*qv[3];
                #pragma unroll
                for (int off = 1; off < 16; off <<= 1) p += __shfl_xor(p, off);
                if (fr == 0)
                    atomicAdd(&scores[row0 + wm + i*16 + quad*4 + r], p * SCL);
            }
        }
    } else {
        // v half: store bf16 with bias
        #pragma unroll
        for (int j = 0; j < 4; j++) {
            const int col = col0 - HD + wn + j*16 + fr;
            const float bb = bv[col];
            #pragma unroll
            for (int i = 0; i < 4; i++) {
                #pragma unroll
                for (int r = 0; r < 4; r++) {
                    const int row = row0 + wm + i*16 + quad*4 + r;
                    v_bf[(size_t)row*HD + col] = f2b(acc[i][j][r] + bb);
                }
            }
        }
    }
}

// ----- gather + softmax + weighted sum of v: one wave per row -----
__global__ __launch_bounds__(256) void gp_attn(
    const float* __restrict__ scores, const int* __restrict__ index,
    const float* __restrict__ mask, const unsigned short* __restrict__ v,
    unsigned short* __restrict__ attn)
{
    const int m = blockIdx.x * 4 + (threadIdx.x >> 6);
    const int lane = threadIdx.x & 63;
    const int b = m >> 10, l = m & 1023;

    const int t = lane & 31;
    const int idx = index[l*KNBR + t];
    const float s = scores[b*LL + idx] + mask[(size_t)m*KNBR + t];

    float mx = s;
    #pragma unroll
    for (int off = 16; off; off >>= 1) mx = fmaxf(mx, __shfl_xor(mx, off));
    const float e = __expf(s - mx);
    float sum = e;
    #pragma unroll
    for (int off = 16; off; off >>= 1) sum += __shfl_xor(sum, off);
    const float w = e / sum;

    const unsigned short* vbase = v + (size_t)(b << 10) * HD + lane*8;
    float a[8] = {};
    #pragma unroll 8
    for (int t2 = 0; t2 < KNBR; t2++) {
        const int   it = __shfl(idx, t2);
        const float wt = __shfl(w,   t2);
        const uint4 pv = *(const uint4*)(vbase + (size_t)it*HD);
        a[0] += wt * b2f_lo(pv.x); a[1] += wt * b2f_hi(pv.x);
        a[2] += wt * b2f_lo(pv.y); a[3] += wt * b2f_hi(pv.y);
        a[4] += wt * b2f_lo(pv.z); a[5] += wt * b2f_hi(pv.z);
        a[6] += wt * b2f_lo(pv.w); a[7] += wt * b2f_hi(pv.w);
    }
    uint4 o;
    o.x = (unsigned int)f2b(a[0]) | ((unsigned int)f2b(a[1]) << 16);
    o.y = (unsigned int)f2b(a[2]) | ((unsigned int)f2b(a[3]) << 16);
    o.z = (unsigned int)f2b(a[4]) | ((unsigned int)f2b(a[5]) << 16);
    o.w = (unsigned int)f2b(a[6]) | ((unsigned int)f2b(a[7]) << 16);
    *(uint4*)&attn[(size_t)m*HD + lane*8] = o;
}

// ------- dense GEMM + residual + LayerNorm fused -------
// Block: 32 rows x full 512 cols. 4 waves, each a 128-col stripe (acc[2][8]).
__global__ __launch_bounds__(256) void dense_ln(
    const unsigned short* __restrict__ A,    // attn_bf, MT x 512
    const unsigned short* __restrict__ W,    // Wd_bf, 512 x 512
    const float* __restrict__ bd, const unsigned short* __restrict__ res,
    const float* __restrict__ ln_g, const float* __restrict__ ln_b,
    float* __restrict__ out)
{
    __shared__ unsigned short As[32 * 32];    // 2 KB
    __shared__ unsigned short Bs[512 * 32];   // 32 KB
    __shared__ float g_s[HD], lb_s[HD];       // 4 KB
    __shared__ float rsum[4][32], rsq[4][32]; // 1 KB

    const int tid  = threadIdx.x;
    const int wave = tid >> 6, lane = tid & 63;
    const int row0 = blockIdx.x * 32;

    // stage gamma/beta
    {
        const int i = tid * 2;
        *(float2*)&g_s[i]  = *(const float2*)&ln_g[i];
        *(float2*)&lb_s[i] = *(const float2*)&ln_b[i];
    }

    const int lrr = lane >> 2;
    const int cc  = lane & 3;
    const int fr   = lane & 15;
    const int quad = lane >> 4;

    f32x4 acc[2][8];
    #pragma unroll
    for (int i = 0; i < 2; i++)
        #pragma unroll
        for (int j = 0; j < 8; j++)
            acc[i][j] = (f32x4){0.f, 0.f, 0.f, 0.f};

    int a_off[2], b_off[8];
    #pragma unroll
    for (int i = 0; i < 2; i++) {
        const int m = i*16 + fr;
        a_off[i] = m*32 + ((quad ^ ((m >> 1) & 3)) << 3);
    }
    #pragma unroll
    for (int j = 0; j < 8; j++) {
        const int n = wave*128 + j*16 + fr;
        b_off[j] = n*32 + ((quad ^ ((n >> 1) & 3)) << 3);
    }

    for (int k0 = 0; k0 < HD; k0 += 32) {
        // B: each wave stages 128 rows (8 glds of 16 rows)
        #pragma unroll
        for (int t = 0; t < 8; t++) {
            const int n = wave*128 + t*16 + lrr;
            const int gch = cc ^ ((n >> 1) & 3);
            const unsigned short* gw = &W[(size_t)n*HD + k0 + gch*8];
            __builtin_amdgcn_global_load_lds(
                (const __attribute__((address_space(1))) void*)gw,
                (__attribute__((address_space(3))) void*)&Bs[(wave*128 + t*16)*32],
                16, 0, 0);
        }
        // A: waves 0,1 stage 16 rows each
        if (wave < 2) {
            const int m = wave*16 + lrr;
            const int gch = cc ^ ((m >> 1) & 3);
            const unsigned short* ga = &A[(size_t)(row0 + m)*HD + k0 + gch*8];
            __builtin_amdgcn_global_load_lds(
                (const __attribute__((address_space(1))) void*)ga,
                (__attribute__((address_space(3))) void*)&As[(wave*16)*32],
                16, 0, 0);
        }
        __syncthreads();

        bf16x8 af[2], bfr[8];
        #pragma unroll
        for (int i = 0; i < 2; i++) af[i] = *(const bf16x8*)&As[a_off[i]];
        #pragma unroll
        for (int j = 0; j < 8; j++) bfr[j] = *(const bf16x8*)&Bs[b_off[j]];
        #pragma unroll
        for (int i = 0; i < 2; i++)
            #pragma unroll
            for (int j = 0; j < 8; j++)
                acc[i][j] = __builtin_amdgcn_mfma_f32_16x16x32_bf16(
                    af[i], bfr[j], acc[i][j], 0, 0, 0);
        __syncthreads();
    }

    // epilogue: val = acc + bd + res; row stats; LN; store fp32
    float bdv[8];
    #pragma unroll
    for (int j = 0; j < 8; j++) bdv[j] = bd[wave*128 + j*16 + fr];

    float s1[2][4], s2[2][4];
    #pragma unroll
    for (int i = 0; i < 2; i++) {
        #pragma unroll
        for (int r = 0; r < 4; r++) {
            const int lrow = i*16 + quad*4 + r;
            const size_t gr = (size_t)(row0 + lrow) * HD;
            float a1 = 0.f, a2 = 0.f;
            #pragma unroll
            for (int j = 0; j < 8; j++) {
                const int col = wave*128 + j*16 + fr;
                float val = acc[i][j][r] + bdv[j] + b2f(res[gr + col]);
                acc[i][j][r] = val;
                a1 += val; a2 += val*val;
            }
            #pragma unroll
            for (int off = 1; off < 16; off <<= 1) {
                a1 += __shfl_xor(a1, off);
                a2 += __shfl_xor(a2, off);
            }
            s1[i][r] = a1; s2[i][r] = a2;
            if (fr == 0) { rsum[wave][lrow] = a1; rsq[wave][lrow] = a2; }
        }
    }
    __syncthreads();

    #pragma unroll
    for (int i = 0; i < 2; i++) {
        #pragma unroll
        for (int r = 0; r < 4; r++) {
            const int lrow = i*16 + quad*4 + r;
            const float tot  = rsum[0][lrow] + rsum[1][lrow] + rsum[2][lrow] + rsum[3][lrow];
            const float tot2 = rsq[0][lrow]  + rsq[1][lrow]  + rsq[2][lrow]  + rsq[3][lrow];
            const float mu  = tot * (1.f/HD);
            const float var = tot2 * (1.f/HD) - mu*mu;
            const float inv = rsqrtf(var + 1e-12f);
            const size_t gr = (size_t)(row0 + lrow) * HD;
            #pragma unroll
            for (int j = 0; j < 8; j++) {
                const int col = wave*128 + j*16 + fr;
                out[gr + col] = (acc[i][j][r] - mu)*inv*g_s[col] + lb_s[col];
            }
        }
    }
}

extern "C" void kernel_launch(void* const* d_in, const int* in_sizes, int n_in,
                              void* d_out, int out_size, void* d_ws, size_t ws_size,
                              hipStream_t stream) {
    const float* user_emb = (const float*)d_in[0];
    const float* item_emb = (const float*)d_in[1];
    const float* mask     = (const float*)d_in[2];
    const int*   index    = (const int*)  d_in[3];
    const float* Wq = (const float*)d_in[4];  const float* bq = (const float*)d_in[5];
    const float* Wk = (const float*)d_in[6];  const float* bk = (const float*)d_in[7];
    const float* Wv = (const float*)d_in[8];  const float* bv = (const float*)d_in[9];
    const float* Wd = (const float*)d_in[10]; const float* bd = (const float*)d_in[11];
    const float* ln_g = (const float*)d_in[12];
    const float* ln_b = (const float*)d_in[13];

    float* out = (float*)d_out;

    // workspace layout
    char* p = (char*)d_ws;
    unsigned short* item_bf = (unsigned short*)p; p += (size_t)MT*HD*2;     // 16.8 MB
    unsigned short* v_bf    = (unsigned short*)p; p += (size_t)MT*HD*2;     // 16.8 MB
    unsigned short* attn_bf = (unsigned short*)p; p += (size_t)MT*HD*2;     // 16.8 MB
    unsigned short* Wkv_bf  = (unsigned short*)p; p += (size_t)2*HD*HD*2;   // 1 MB
    unsigned short* Wd_bf   = (unsigned short*)p; p += (size_t)HD*HD*2;     // 0.5 MB
    float* q      = (float*)p; p += 16*HD*4;
    float* scores = (float*)p; p += MT*4;

    conv_bf<<<MT*HD/4/256, 256, 0, stream>>>(item_emb, item_bf, MT*HD);
    conv_w3<<<3*HD*HD/4/256, 256, 0, stream>>>(Wk, Wv, Wd, Wkv_bf, Wd_bf);

    gp_q<<<2048, 256, 0, stream>>>(user_emb, Wq, bq, q);
    scores_init<<<16, 256, 0, stream>>>(q, bk, scores);

    // fused K+V GEMM; k half feeds scores atomically, v half stored bf16
    dim3 gkv(MT/128, 8);
    gemm_kv<<<gkv, 256, 0, stream>>>(item_bf, Wkv_bf, q, bv, scores, v_bf);

    gp_attn<<<MT/4, 256, 0, stream>>>(scores, index, mask, v_bf, attn_bf);

    // dense + residual + LN fused -> fp32 out
    dense_ln<<<MT/32, 256, 0, stream>>>(attn_bf, Wd_bf, bd, item_bf,
                                        ln_g, ln_b, out);
}